// Round 6
// baseline (287.957 us; speedup 1.0000x reference)
//
#include <hip/hip_runtime.h>
#include <cstdint>
#include <cstddef>

// B=1, L=2048, DIM=512, H=8, D=64, STEPS=1024.  R14: single fused kernel.
// R14 change: R9-R13 falsified every in-kernel theory for the ~40us residual
//   (B staging x4 variants, store coalescing) -- all land 137-143 while the
//   modeled work is <=5us.  No kernel has been rocprof-visible since R8 (all
//   < the 43us fills).  So: fuse prep+qs_ln+flash6+gemm into ONE dispatch
//   (256 blocks x 512 thr, 1 block/CU, 145.5KB LDS) with a monotonic-epoch
//   device-atomic grid barrier (grid<=CU count -> capacity-safe; no reset ->
//   graph/rocprof-replay safe).  Phase math bit-identical (A/B verbatim; D's
//   nt-loop redistributed over 8 waves, per-element MFMA chains unchanged).
//   Wins if the residual was launch/gap/dispatch overhead; if not, the fused
//   kernel MUST appear in top-5 with counters -> attribution at last.
// Pre-committed: ~100-118 => overhead confirmed; ~135-142 + visible ~50us
//   kernel => real stall, read its counters next; visible ~20us + total ~140
//   => harness floor (roofline).  absmax must stay 1.831e-4 exactly.

typedef __attribute__((ext_vector_type(8))) short short8;
typedef __attribute__((ext_vector_type(4))) float f32x4;

#define MFMA16(a, b, c) __builtin_amdgcn_mfma_f32_16x16x32_bf16((a), (b), (c), 0, 0, 0)

static constexpr size_t B_ATTB = 0;                        // bf16 [2048][512] = 2 MB
static constexpr size_t B_UB   = (size_t)2 * 1024 * 1024;  // bf16 [8][2048][128] = 4 MB
static constexpr size_t B_WB   = B_UB + (size_t)4 * 1024 * 1024;
static constexpr size_t B_VT   = B_WB + (size_t)4 * 1024 * 1024;   // bf16 [8][64][2048]
static constexpr size_t B_WQT  = B_VT + (size_t)2 * 1024 * 1024;   // frag-packed, 1 MB
static constexpr size_t B_WOT  = B_WQT + (size_t)1 * 1024 * 1024;  // bf16 [512][512]

__device__ __forceinline__ unsigned short f2bf(float f) {
  unsigned u = __float_as_uint(f);
  return (unsigned short)((u + 0x7FFFu + ((u >> 16) & 1u)) >> 16);
}

// async global->LDS DMA, 16B per lane; lds dest = wave-uniform base + lane*16
__device__ __forceinline__ void dma16(const unsigned short* g, unsigned char* l) {
  __builtin_amdgcn_global_load_lds((const unsigned int*)g, (unsigned int*)l,
                                   16, 0, 0);
}

// ---- monotonic-epoch grid barrier: no reset, replay-safe, grid<=256 CUs ----
__device__ unsigned g_bar[4];   // zero at module load; counts forever

__device__ __forceinline__ void gridbar(int i) {
  __syncthreads();
  if (threadIdx.x == 0) {
    __threadfence();                       // publish this block's writes
    unsigned old = atomicAdd(&g_bar[i], 1u);          // device scope
    unsigned target = (old / 256u + 1u) * 256u;       // end of this epoch
    while (__hip_atomic_load(&g_bar[i], __ATOMIC_ACQUIRE,
                             __HIP_MEMORY_SCOPE_AGENT) < target)
      __builtin_amdgcn_s_sleep(2);
    __threadfence();                       // acquire: invalidate stale caches
  }
  __syncthreads();
}

// ======================= the whole pipeline, fused =========================
__global__ __launch_bounds__(512, 1) void k_fused(const float* __restrict__ x,
    const float* __restrict__ Wq, const float* __restrict__ bq,
    const float* __restrict__ lnw, const float* __restrict__ lnb,
    const float* __restrict__ fr, const float* __restrict__ psh,
    const float* __restrict__ Wo, const float* __restrict__ bo,
    unsigned short* __restrict__ vT, unsigned short* __restrict__ WqTp,
    unsigned short* __restrict__ WoT, unsigned short* __restrict__ Ub,
    unsigned short* __restrict__ Wb, unsigned short* __restrict__ attb,
    float* __restrict__ out) {
  __shared__ __align__(16) unsigned char smem[148992];   // 145.5 KB union
  const int t = threadIdx.x, b = blockIdx.x;
  const int w = t >> 6, lane = t & 63, m = lane & 15, quad = lane >> 4;

  // ---------------- phase A: prep (448 units over 256 blocks x 2 halves) ----
  {
    const int ht = t >> 8, tt = t & 255;
    const int u = ht ? (b + 256) : b;
    const bool act = (ht == 0) || (b < 192);
    float* tlh = (float*)(smem + ht * 16640);
    if (act) {
      if (u < 256) {
        const int i0 = (u >> 3) * 64, h = u & 7;
        #pragma unroll
        for (int it = 0; it < 16; ++it) {
          int n = tt + 256 * it;
          int r = n >> 6, c = n & 63;
          tlh[r * 65 + c] = x[(size_t)(i0 + r) * 512 + h * 64 + c];
        }
      } else if (u < 384) {
        const int bb = u - 256;
        const int k0 = (bb >> 4) * 64, n0 = (bb & 15) * 64;
        #pragma unroll
        for (int it = 0; it < 16; ++it) {
          int n = tt + 256 * it;
          int r = n >> 6, c = n & 63;
          tlh[r * 65 + c] = Wq[(size_t)(k0 + r) * 1024 + n0 + c];
        }
      } else {
        const int bb = u - 384;
        const int k0 = (bb >> 3) * 64, n0 = (bb & 7) * 64;
        #pragma unroll
        for (int it = 0; it < 16; ++it) {
          int n = tt + 256 * it;
          int r = n >> 6, c = n & 63;
          tlh[r * 65 + c] = Wo[(size_t)(k0 + r) * 512 + n0 + c];
        }
      }
    }
    __syncthreads();
    if (act) {
      if (u < 256) {
        const int i0 = (u >> 3) * 64, h = u & 7;
        #pragma unroll
        for (int it = 0; it < 16; ++it) {
          int n = tt + 256 * it;
          int d = n >> 6, ii = n & 63;
          vT[(size_t)(h * 64 + d) * 2048 + i0 + ii] = f2bf(tlh[ii * 65 + d]);
        }
      } else if (u < 384) {
        const int bb = u - 256;
        const int k0 = (bb >> 4) * 64, n0 = (bb & 15) * 64;
        #pragma unroll
        for (int it = 0; it < 16; ++it) {
          int n = tt + 256 * it;
          int rr = n >> 6, cc = n & 63;
          int nn = n0 + rr, kk = k0 + cc;
          int nt = nn >> 4, mm = nn & 15;
          int kc32 = kk >> 5, qd = (kk >> 3) & 3, j = kk & 7;
          WqTp[(((size_t)nt * 16 + kc32) * 64 + qd * 16 + mm) * 8 + j] =
              f2bf(tlh[cc * 65 + rr]);
        }
      } else {
        const int bb = u - 384;
        const int k0 = (bb >> 3) * 64, n0 = (bb & 7) * 64;
        #pragma unroll
        for (int it = 0; it < 16; ++it) {
          int n = tt + 256 * it;
          int rr = n >> 6, cc = n & 63;
          WoT[(size_t)(n0 + rr) * 512 + k0 + cc] = f2bf(tlh[cc * 65 + rr]);
        }
      }
    }
  }
  gridbar(0);

  // ---------------- phase B: qs-GEMM + LN + activations + features ---------
  if (b < 128) {
    float* s_amp = (float*)(smem);            // aliases dead B buf 0
    float* s_ph  = (float*)(smem + 65536);    // aliases dead B buf 1
    unsigned short* s_a = (unsigned short*)(smem + 131072);
    float* red  = (float*)(smem + 147712);
    float* red2 = (float*)(smem + 148736);
    const int r0 = b * 16;
    const unsigned short* gB = WqTp + (size_t)w * 8192 + (size_t)lane * 8;
    #pragma unroll
    for (int it = 0; it < 8; ++it)
      dma16(gB + (size_t)it * 65536, smem + (it * 8 + w) * 1024);
    {
      const int row = t >> 5, cs = (t & 31) * 16;
      const float4* xr = (const float4*)(x + (size_t)(r0 + row) * 512 + cs);
      unsigned short tmp[16];
      #pragma unroll
      for (int q4 = 0; q4 < 4; ++q4) {
        float4 v = xr[q4];
        tmp[q4 * 4 + 0] = f2bf(v.x); tmp[q4 * 4 + 1] = f2bf(v.y);
        tmp[q4 * 4 + 2] = f2bf(v.z); tmp[q4 * 4 + 3] = f2bf(v.w);
      }
      *(short8*)(s_a + row * 520 + cs)     = *(short8*)(tmp);
      *(short8*)(s_a + row * 520 + cs + 8) = *(short8*)(tmp + 8);
    }
    __syncthreads();  // s_a ready + tile-0 DMAs drained
    f32x4 acc[8] = {{0,0,0,0},{0,0,0,0},{0,0,0,0},{0,0,0,0},
                    {0,0,0,0},{0,0,0,0},{0,0,0,0},{0,0,0,0}};
    for (int kc = 0; kc < 16; ++kc) {
      const int cur = kc & 1;
      if (kc < 15) {
        const unsigned short* g = gB + (size_t)(kc + 1) * 512;
        #pragma unroll
        for (int it = 0; it < 8; ++it)
          dma16(g + (size_t)it * 65536,
                smem + (cur ^ 1) * 65536 + (it * 8 + w) * 1024);
      }
      short8 af = *(const short8*)(s_a + m * 520 + kc * 32 + quad * 8);
      #pragma unroll
      for (int nt = 0; nt < 8; ++nt) {
        short8 bf = *(const short8*)(smem + cur * 65536 +
                                     (w * 8 + nt) * 1024 + lane * 16);
        acc[nt] = MFMA16(af, bf, acc[nt]);
      }
      __syncthreads();
    }
    #pragma unroll
    for (int nt = 0; nt < 8; ++nt) {
      float bv = bq[w * 128 + nt * 16 + m];
      #pragma unroll
      for (int r = 0; r < 4; ++r) acc[nt][r] += bv;
    }
    float s1[4] = {0, 0, 0, 0}, s2[4] = {0, 0, 0, 0};
    #pragma unroll
    for (int r = 0; r < 4; ++r)
      #pragma unroll
      for (int nt = 0; nt < 8; ++nt) {
        float v = acc[nt][r];
        s1[r] += v; s2[r] += v * v;
      }
    #pragma unroll
    for (int off = 1; off < 16; off <<= 1)
      #pragma unroll
      for (int r = 0; r < 4; ++r) {
        s1[r] += __shfl_xor(s1[r], off, 64);
        s2[r] += __shfl_xor(s2[r], off, 64);
      }
    if (m == 0)
      #pragma unroll
      for (int r = 0; r < 4; ++r) {
        red[(w * 16 + quad * 4 + r) * 2]     = s1[r];
        red[(w * 16 + quad * 4 + r) * 2 + 1] = s2[r];
      }
    __syncthreads();
    float mu[4], rstd[4];
    #pragma unroll
    for (int r = 0; r < 4; ++r) {
      int row = quad * 4 + r;
      float S = 0, S2 = 0;
      #pragma unroll
      for (int wp = 0; wp < 8; ++wp) {
        S  += red[(wp * 16 + row) * 2];
        S2 += red[(wp * 16 + row) * 2 + 1];
      }
      mu[r] = S * (1.0f / 1024.0f);
      float var = S2 * (1.0f / 1024.0f) - mu[r] * mu[r];
      rstd[r] = 1.0f / sqrtf(var + 1e-5f);
    }
    float y[8][4];
    #pragma unroll
    for (int nt = 0; nt < 8; ++nt) {
      int c = w * 128 + nt * 16 + m;
      float gw = lnw[c], gb = lnb[c];
      #pragma unroll
      for (int r = 0; r < 4; ++r)
        y[nt][r] = (acc[nt][r] - mu[r]) * rstd[r] * gw + gb;
    }
    const float PI_F = 3.14159265358979323846f;
    float a[8][4];
    if (w < 4) {
      float na[4] = {0, 0, 0, 0};
      #pragma unroll
      for (int nt = 0; nt < 8; ++nt)
        #pragma unroll
        for (int r = 0; r < 4; ++r) {
          float v = __builtin_amdgcn_rcpf(1.0f + __expf(-y[nt][r]));
          a[nt][r] = v;
          na[r] += v * v;
        }
      #pragma unroll
      for (int off = 1; off < 16; off <<= 1)
        #pragma unroll
        for (int r = 0; r < 4; ++r) na[r] += __shfl_xor(na[r], off, 64);
      if (m == 0)
        #pragma unroll
        for (int r = 0; r < 4; ++r) red2[w * 16 + quad * 4 + r] = na[r];
    } else {
      #pragma unroll
      for (int nt = 0; nt < 8; ++nt)
        #pragma unroll
        for (int r = 0; r < 4; ++r) {
          float e2 = __expf(2.0f * y[nt][r]);
          float p = (1.0f - 2.0f * __builtin_amdgcn_rcpf(e2 + 1.0f)) * PI_F;
          s_ph[(quad * 4 + r) * 516 + (w - 4) * 128 + nt * 16 + m] = p;
        }
    }
    __syncthreads();   // red2 + s_ph ready
    if (w < 4) {
      float inv[4];
      #pragma unroll
      for (int r = 0; r < 4; ++r) {
        int row = quad * 4 + r;
        float N = red2[row] + red2[16 + row] + red2[32 + row] + red2[48 + row];
        inv[r] = 1.0f / (sqrtf(N) + 1e-8f);
      }
      #pragma unroll
      for (int nt = 0; nt < 8; ++nt)
        #pragma unroll
        for (int r = 0; r < 4; ++r)
          s_amp[(quad * 4 + r) * 516 + w * 128 + nt * 16 + m] = a[nt][r] * inv[r];
    }
    __syncthreads();   // s_amp ready
    {
      const double GAM = 1024.0 / 1023.0;
      const int h  = lane >> 3;
      const int d0 = (lane & 7) * 8;
      const float c1  = (float)((double)fr[h]  * GAM);
      const float s1g = (float)((double)psh[h] * GAM);
      #pragma unroll
      for (int half = 0; half < 2; ++half) {
        const int row = half * 8 + w;
        const int i   = r0 + row;
        const float* ap = s_amp + row * 516 + h * 64 + d0;
        const float* pp = s_ph  + row * 516 + h * 64 + d0;
        short8 uc, us, wc, wsn;
        #pragma unroll
        for (int j = 0; j < 8; ++j) {
          float af = ap[j], p = pp[j];
          float A  = fmaf(p, c1, s1g);
          float Bp = p * c1;
          float cA, sA, cB, sB;
          __sincosf(A, &sA, &cA);
          __sincosf(Bp, &sB, &cB);
          uc[j]  = (short)f2bf(af * cA); us[j]  = (short)f2bf(af * sA);
          wc[j]  = (short)f2bf(af * cB); wsn[j] = (short)f2bf(af * sB);
        }
        size_t base = ((size_t)h * 2048 + i) * 128 + d0;
        *(short8*)(Ub + base)      = uc;
        *(short8*)(Ub + base + 64) = us;
        *(short8*)(Wb + base)      = wc;
        *(short8*)(Wb + base + 64) = wsn;
      }
    }
  }
  gridbar(1);

  // ---------------- phase C: flash attention (256 units) -------------------
  {
    unsigned char* sw0 = smem;                 // 2 x 128*272
    unsigned char* sv0 = smem + 69632;         // 2 x 64*272
    unsigned char* sp0 = smem + 104448;        // 2 x 64*272
    const int qt = b & 31, h = b >> 5;
    const int q0 = qt * 64;
    const int wave = w;
    const int qg = wave & 3, dh = wave >> 2;
    const int sr = t >> 2, sp = t & 3;
    const int vr = t >> 3, vp = t & 7;
    short8 afr[4][4];
    #pragma unroll
    for (int g = 0; g < 4; ++g) {
      const unsigned short* urow = Ub + ((size_t)h * 2048 + q0 + g * 16 + m) * 128;
      #pragma unroll
      for (int fs = 0; fs < 4; ++fs)
        afr[g][fs] = *(const short8*)(urow + fs * 32 + quad * 8);
    }
    short8 ones;
    #pragma unroll
    for (int j = 0; j < 8; ++j) ones[j] = (short)0x3F80;
    f32x4 oacc[2] = {{0,0,0,0},{0,0,0,0}};
    f32x4 dacc = {0, 0, 0, 0};
    const unsigned short* wgbase = Wb + (size_t)h * 2048 * 128 + (size_t)sr * 128;
    const unsigned short* vgbase = vT + ((size_t)h * 64 + vr) * 2048;
    #pragma unroll
    for (int it = 0; it < 4; ++it)
      *(short8*)(sw0 + sr * 272 + sp * 64 + it * 16) =
        *(const short8*)(wgbase + sp * 32 + it * 8);
    #pragma unroll
    for (int it = 0; it < 2; ++it)
      *(short8*)(sv0 + vr * 272 + vp * 32 + it * 16) =
        *(const short8*)(vgbase + vp * 16 + it * 8);
    __syncthreads();
    for (int kt = 0; kt < 16; ++kt) {
      const int cur = kt & 1;
      unsigned char* swc = sw0 + cur * 34816;
      unsigned char* svc = sv0 + cur * 17408;
      unsigned char* spc = sp0 + cur * 17408;
      short8 wst[4], vst[2];
      const bool has = (kt < 15);
      if (has) {
        const unsigned short* wg = wgbase + (size_t)(kt + 1) * 128 * 128;
        #pragma unroll
        for (int it = 0; it < 4; ++it)
          wst[it] = *(const short8*)(wg + sp * 32 + it * 8);
        const unsigned short* vg = vgbase + (kt + 1) * 128;
        #pragma unroll
        for (int it = 0; it < 2; ++it)
          vst[it] = *(const short8*)(vg + vp * 16 + it * 8);
      }
      f32x4 sc[4] = {{0,0,0,0},{0,0,0,0},{0,0,0,0},{0,0,0,0}};
      #pragma unroll
      for (int fs = 0; fs < 4; ++fs) {
        short8 bfr = *(const short8*)(swc + (wave * 16 + m) * 272 + fs * 64 + quad * 16);
        #pragma unroll
        for (int g = 0; g < 4; ++g)
          sc[g] = MFMA16(afr[g][fs], bfr, sc[g]);
      }
      #pragma unroll
      for (int g = 0; g < 4; ++g)
        #pragma unroll
        for (int r = 0; r < 4; ++r) {
          float p = __expf(sc[g][r] * 0.125f);
          *(unsigned short*)(spc + (g * 16 + quad * 4 + r) * 272 +
                             (wave * 16 + m) * 2) = f2bf(p);
        }
      short8 vf[4][2];
      #pragma unroll
      for (int k2 = 0; k2 < 4; ++k2)
        #pragma unroll
        for (int dt = 0; dt < 2; ++dt)
          vf[k2][dt] = *(const short8*)(svc + (dh * 32 + dt * 16 + m) * 272 +
                                        k2 * 64 + quad * 16);
      if (has) {
        unsigned char* swn = sw0 + (cur ^ 1) * 34816;
        unsigned char* svn = sv0 + (cur ^ 1) * 17408;
        #pragma unroll
        for (int it = 0; it < 4; ++it)
          *(short8*)(swn + sr * 272 + sp * 64 + it * 16) = wst[it];
        #pragma unroll
        for (int it = 0; it < 2; ++it)
          *(short8*)(svn + vr * 272 + vp * 32 + it * 16) = vst[it];
      }
      __syncthreads();
      #pragma unroll
      for (int k2 = 0; k2 < 4; ++k2) {
        short8 pf = *(const short8*)(spc + (qg * 16 + m) * 272 + k2 * 64 + quad * 16);
        dacc = MFMA16(pf, ones, dacc);
        #pragma unroll
        for (int dt = 0; dt < 2; ++dt)
          oacc[dt] = MFMA16(pf, vf[k2][dt], oacc[dt]);
      }
    }
    float invd[4];
    #pragma unroll
    for (int r = 0; r < 4; ++r) invd[r] = 1.0f / dacc[r];
    #pragma unroll
    for (int dt = 0; dt < 2; ++dt)
      #pragma unroll
      for (int r = 0; r < 4; ++r)
        attb[(size_t)(q0 + qg * 16 + quad * 4 + r) * 512 + h * 64 +
             dh * 32 + dt * 16 + m] = f2bf(oacc[dt][r] * invd[r]);
  }
  gridbar(2);

  // ---------------- phase D: out GEMM (256 units, 8 waves each) ------------
  {
    unsigned char* s_ga = smem;
    unsigned char* s_gb = smem + 8704;
    const int m0 = (b & 31) * 64, n0 = (b >> 5) * 64;
    const int rw = w & 3, ch = w >> 2;
    const int sr8 = t >> 3, sp8 = t & 7;
    f32x4 acc2[2] = {{0,0,0,0},{0,0,0,0}};
    for (int kc = 0; kc < 512; kc += 64) {
      *(short8*)(s_ga + sr8 * 136 + sp8 * 16) =
        *(const short8*)(attb + (size_t)(m0 + sr8) * 512 + kc + sp8 * 8);
      *(short8*)(s_gb + sr8 * 136 + sp8 * 16) =
        *(const short8*)(WoT + (size_t)(n0 + sr8) * 512 + kc + sp8 * 8);
      __syncthreads();
      #pragma unroll
      for (int k2 = 0; k2 < 2; ++k2) {
        short8 af = *(const short8*)(s_ga + (rw * 16 + m) * 136 + k2 * 64 + quad * 16);
        #pragma unroll
        for (int nt2 = 0; nt2 < 2; ++nt2) {
          short8 bf = *(const short8*)(s_gb + ((ch * 2 + nt2) * 16 + m) * 136 +
                                       k2 * 64 + quad * 16);
          acc2[nt2] = MFMA16(af, bf, acc2[nt2]);
        }
      }
      __syncthreads();
    }
    #pragma unroll
    for (int nt2 = 0; nt2 < 2; ++nt2) {
      int col = n0 + (ch * 2 + nt2) * 16 + m;
      float bv = bo[col];
      #pragma unroll
      for (int r = 0; r < 4; ++r) {
        int row = m0 + rw * 16 + quad * 4 + r;
        out[(size_t)row * 512 + col] = acc2[nt2][r] + bv;
      }
    }
  }
}

extern "C" void kernel_launch(void* const* d_in, const int* in_sizes, int n_in,
                              void* d_out, int out_size, void* d_ws, size_t ws_size,
                              hipStream_t stream) {
  (void)in_sizes; (void)n_in; (void)out_size; (void)ws_size;
  const float* x   = (const float*)d_in[0];
  const float* Wq  = (const float*)d_in[1];
  const float* bq  = (const float*)d_in[2];
  const float* lnw = (const float*)d_in[3];
  const float* lnb = (const float*)d_in[4];
  const float* fr  = (const float*)d_in[5];
  const float* ps  = (const float*)d_in[6];
  const float* Wo  = (const float*)d_in[7];
  const float* bo  = (const float*)d_in[8];
  // d_in[9] = cos_table: unused (smooth-cos factorization)
  char* ws = (char*)d_ws;
  unsigned short* attb = (unsigned short*)(ws + B_ATTB);
  unsigned short* Ub   = (unsigned short*)(ws + B_UB);
  unsigned short* Wb   = (unsigned short*)(ws + B_WB);
  unsigned short* vT   = (unsigned short*)(ws + B_VT);
  unsigned short* WqTp = (unsigned short*)(ws + B_WQT);
  unsigned short* WoT  = (unsigned short*)(ws + B_WOT);
  float* out = (float*)d_out;

  k_fused<<<256, 512, 0, stream>>>(x, Wq, bq, lnw, lnb, fr, ps, Wo, bo,
                                   vT, WqTp, WoT, Ub, Wb, attb, out);
}

// Round 7
// 140.216 us; speedup vs baseline: 2.0537x; 2.0537x over previous
//
#include <hip/hip_runtime.h>
#include <cstdint>
#include <cstddef>

// B=1, L=2048, DIM=512, H=8, D=64, STEPS=1024.  R15: TLP restructure of B-phase.
// R14's fused diagnostic finally produced counters: VALUBusy 4.8%, MfmaUtil
// 3.1%, HBM 3.2%, Occupancy 23.6% -> latency-bound at ~2 waves/SIMD.  Every
// slow config this session ran 512-thr/1-block-per-CU grids (<=2 waves/SIMD);
// dependent MFMA/LDS/L2 chains stall ~96% and nothing covers the stall.
// R15: revert fusion; split k_qs_ln for occupancy (Guideline 1):
//   k_qs_gemm: 2048 blocks x 256 thr (~8 waves/SIMD machine-wide); wave = one
//     16x16 tile; B-frags straight from L2 (no staging, no K-loop barriers);
//     writes qs(+bias) f32 + per-coltile partial sums (no atomics/zeroing).
//   k_ln_feat: 2048 row-blocks x 256 thr; combine partials -> LN -> sigmoid/
//     tanh/sincos features, packed 4B stores.
// prep/flash6/gemm unchanged.  Reduction ORDER changes slightly (absmax may
// drift ulps); per-element formulas identical.
//
//  pipeline: k_prep -> k_qs_gemm -> k_ln_feat -> k_flash6 -> k_gemm(out)

typedef __attribute__((ext_vector_type(8))) short short8;
typedef __attribute__((ext_vector_type(4))) float f32x4;

#define MFMA16(a, b, c) __builtin_amdgcn_mfma_f32_16x16x32_bf16((a), (b), (c), 0, 0, 0)

static constexpr size_t B_ATTB = 0;                        // bf16 [2048][512] = 2 MB
static constexpr size_t B_UB   = (size_t)2 * 1024 * 1024;  // bf16 [8][2048][128] = 4 MB
static constexpr size_t B_WB   = B_UB + (size_t)4 * 1024 * 1024;
static constexpr size_t B_VT   = B_WB + (size_t)4 * 1024 * 1024;   // bf16 [8][64][2048]
static constexpr size_t B_WQT  = B_VT + (size_t)2 * 1024 * 1024;   // frag-packed, 1 MB
static constexpr size_t B_WOT  = B_WQT + (size_t)1 * 1024 * 1024;  // bf16 [512][512]
static constexpr size_t B_QS   = (size_t)14 * 1024 * 1024;         // f32 [2048][1024] = 8 MB
static constexpr size_t B_PST  = (size_t)23 * 1024 * 1024;         // f32 [2048][64][2] = 1 MB

__device__ __forceinline__ unsigned short f2bf(float f) {
  unsigned u = __float_as_uint(f);
  return (unsigned short)((u + 0x7FFFu + ((u >> 16) & 1u)) >> 16);
}

// ---------------- prep: x -> vT;  Wq -> WqTp (frag-packed);  Wo -> WoT ----------
__global__ __launch_bounds__(256) void k_prep(const float* __restrict__ x,
    const float* __restrict__ Wq, const float* __restrict__ Wo,
    unsigned short* __restrict__ vT, unsigned short* __restrict__ WqTp,
    unsigned short* __restrict__ WoT) {
  __shared__ float tl[64 * 65];
  const int t = threadIdx.x, b = blockIdx.x;
  if (b < 256) {
    const int i0 = (b >> 3) * 64, h = b & 7;
    #pragma unroll
    for (int it = 0; it < 16; ++it) {
      int n = t + 256 * it;
      int r = n >> 6, c = n & 63;
      tl[r * 65 + c] = x[(size_t)(i0 + r) * 512 + h * 64 + c];
    }
    __syncthreads();
    #pragma unroll
    for (int it = 0; it < 16; ++it) {
      int n = t + 256 * it;
      int d = n >> 6, ii = n & 63;
      vT[(size_t)(h * 64 + d) * 2048 + i0 + ii] = f2bf(tl[ii * 65 + d]);
    }
  } else if (b < 384) {
    const int bb = b - 256;
    const int k0 = (bb >> 4) * 64, n0 = (bb & 15) * 64;
    #pragma unroll
    for (int it = 0; it < 16; ++it) {
      int n = t + 256 * it;
      int r = n >> 6, c = n & 63;
      tl[r * 65 + c] = Wq[(size_t)(k0 + r) * 1024 + n0 + c];
    }
    __syncthreads();
    #pragma unroll
    for (int it = 0; it < 16; ++it) {
      int n = t + 256 * it;
      int rr = n >> 6, cc = n & 63;       // rr = n-local, cc = k-local
      int nn = n0 + rr, kk = k0 + cc;
      int nt = nn >> 4, mm = nn & 15;
      int kc32 = kk >> 5, qd = (kk >> 3) & 3, j = kk & 7;
      WqTp[(((size_t)nt * 16 + kc32) * 64 + qd * 16 + mm) * 8 + j] =
          f2bf(tl[cc * 65 + rr]);
    }
  } else {
    const int bb = b - 384;
    const int k0 = (bb >> 3) * 64, n0 = (bb & 7) * 64;
    #pragma unroll
    for (int it = 0; it < 16; ++it) {
      int n = t + 256 * it;
      int r = n >> 6, c = n & 63;
      tl[r * 65 + c] = Wo[(size_t)(k0 + r) * 512 + n0 + c];
    }
    __syncthreads();
    #pragma unroll
    for (int it = 0; it < 16; ++it) {
      int n = t + 256 * it;
      int rr = n >> 6, cc = n & 63;
      WoT[(size_t)(n0 + rr) * 512 + k0 + cc] = f2bf(tl[cc * 65 + rr]);
    }
  }
}

// -------- B1a: qs GEMM, one 16x16 tile per wave, high TLP -------------------
// grid 2048 = 128 rowtiles x 16 colgroups; block 256 thr = 4 waves; wave w
// owns coltile ct = cg*4+w (16 cols).  B-frags read straight from L2; no
// K-loop barrier.  Writes qs(+bias) f32 and partial (S,S2) per (row, ct).
__global__ __launch_bounds__(256) void k_qs_gemm(const float* __restrict__ x,
    const unsigned short* __restrict__ WqTp, const float* __restrict__ bq,
    float* __restrict__ qs, float* __restrict__ pst) {
  __shared__ __align__(16) unsigned short s_a[16 * 520];
  __shared__ float s_q[16 * 68];
  const int t = threadIdx.x;
  const int rt = blockIdx.x >> 4, cg = blockIdx.x & 15;
  const int w = t >> 6, lane = t & 63, m = lane & 15, quad = lane >> 4;
  const int ct = cg * 4 + w;
  {  // stage A rows rt*16..+16 (bf16), 32 f32 per thread
    const int row = t >> 4, cs = (t & 15) * 32;
    const float4* xr = (const float4*)(x + (size_t)(rt * 16 + row) * 512 + cs);
    unsigned short tmp[32];
    #pragma unroll
    for (int q4 = 0; q4 < 8; ++q4) {
      float4 v = xr[q4];
      tmp[q4 * 4 + 0] = f2bf(v.x); tmp[q4 * 4 + 1] = f2bf(v.y);
      tmp[q4 * 4 + 2] = f2bf(v.z); tmp[q4 * 4 + 3] = f2bf(v.w);
    }
    #pragma unroll
    for (int q8 = 0; q8 < 4; ++q8)
      *(short8*)(s_a + row * 520 + cs + q8 * 8) = *(short8*)(tmp + q8 * 8);
  }
  __syncthreads();
  f32x4 acc = {0, 0, 0, 0};
  const unsigned short* bp = WqTp + ((size_t)ct * 16 * 64 + lane) * 8;
  #pragma unroll
  for (int kc = 0; kc < 16; ++kc) {
    short8 af = *(const short8*)(s_a + m * 520 + kc * 32 + quad * 8);
    short8 bf = *(const short8*)(bp + (size_t)kc * 512);
    acc = MFMA16(af, bf, acc);
  }
  {  // bias
    float bv = bq[ct * 16 + m];
    #pragma unroll
    for (int r = 0; r < 4; ++r) acc[r] += bv;
  }
  // partial row stats over this ct's 16 cols
  float s1[4], s2[4];
  #pragma unroll
  for (int r = 0; r < 4; ++r) { s1[r] = acc[r]; s2[r] = acc[r] * acc[r]; }
  #pragma unroll
  for (int off = 1; off < 16; off <<= 1)
    #pragma unroll
    for (int r = 0; r < 4; ++r) {
      s1[r] += __shfl_xor(s1[r], off, 64);
      s2[r] += __shfl_xor(s2[r], off, 64);
    }
  if (m == 0)
    #pragma unroll
    for (int r = 0; r < 4; ++r) {
      float2 pv = {s1[r], s2[r]};
      *(float2*)(pst + ((size_t)(rt * 16 + quad * 4 + r) * 64 + ct) * 2) = pv;
    }
  // qs tile -> LDS -> coalesced f32 store
  #pragma unroll
  for (int r = 0; r < 4; ++r)
    s_q[(quad * 4 + r) * 68 + w * 16 + m] = acc[r];
  __syncthreads();
  {
    const int row = t >> 4, c4 = (t & 15) * 4;
    float4 v = *(const float4*)(s_q + row * 68 + c4);
    *(float4*)(qs + (size_t)(rt * 16 + row) * 1024 + cg * 64 + c4) = v;
  }
}

// -------- B1b: LN + activations + cos/sin features, one row per block -------
// grid 2048 rows; 256 thr; thread owns amp cols {2t,2t+1} and phase cols
// {512+2t, 512+2t+1} (same (h,d) pair as its amp cols -> no exchange).
__global__ __launch_bounds__(256) void k_ln_feat(const float* __restrict__ qs,
    const float* __restrict__ pst, const float* __restrict__ lnw,
    const float* __restrict__ lnb, const float* __restrict__ fr,
    const float* __restrict__ psh, unsigned short* __restrict__ Ub,
    unsigned short* __restrict__ Wb) {
  __shared__ float bc[2];
  __shared__ float rna[4];
  const int row = blockIdx.x, t = threadIdx.x;
  const int w = t >> 6, lane = t & 63;
  // combine the 64 per-coltile partials (wave 0)
  if (w == 0) {
    float2 p = *(const float2*)(pst + ((size_t)row * 64 + lane) * 2);
    float S = p.x, S2 = p.y;
    #pragma unroll
    for (int off = 1; off < 64; off <<= 1) {
      S  += __shfl_xor(S, off, 64);
      S2 += __shfl_xor(S2, off, 64);
    }
    if (lane == 0) { bc[0] = S; bc[1] = S2; }
  }
  __syncthreads();
  const float mu = bc[0] * (1.0f / 1024.0f);
  const float var = bc[1] * (1.0f / 1024.0f) - mu * mu;
  const float rstd = 1.0f / sqrtf(var + 1e-5f);
  const int pc = t * 2;
  float2 qa = *(const float2*)(qs + (size_t)row * 1024 + pc);
  float2 qp = *(const float2*)(qs + (size_t)row * 1024 + 512 + pc);
  const float ya0 = (qa.x - mu) * rstd * lnw[pc]     + lnb[pc];
  const float ya1 = (qa.y - mu) * rstd * lnw[pc + 1] + lnb[pc + 1];
  const float yp0 = (qp.x - mu) * rstd * lnw[512 + pc]     + lnb[512 + pc];
  const float yp1 = (qp.y - mu) * rstd * lnw[512 + pc + 1] + lnb[512 + pc + 1];
  const float a0 = __builtin_amdgcn_rcpf(1.0f + __expf(-ya0));
  const float a1 = __builtin_amdgcn_rcpf(1.0f + __expf(-ya1));
  float na = a0 * a0 + a1 * a1;
  #pragma unroll
  for (int off = 1; off < 64; off <<= 1) na += __shfl_xor(na, off, 64);
  if (lane == 0) rna[w] = na;
  __syncthreads();
  const float N = rna[0] + rna[1] + rna[2] + rna[3];
  const float inv = 1.0f / (sqrtf(N) + 1e-8f);
  const float PI_F = 3.14159265358979323846f;
  const float e20 = __expf(2.0f * yp0);
  const float e21 = __expf(2.0f * yp1);
  const float p0 = (1.0f - 2.0f * __builtin_amdgcn_rcpf(e20 + 1.0f)) * PI_F;
  const float p1 = (1.0f - 2.0f * __builtin_amdgcn_rcpf(e21 + 1.0f)) * PI_F;
  const double GAM = 1024.0 / 1023.0;   // table-step rescale (linspace endpoint)
  const int h = pc >> 6, d = pc & 63;
  const float c1  = (float)((double)fr[h]  * GAM);
  const float s1g = (float)((double)psh[h] * GAM);
  const float af0 = a0 * inv, af1 = a1 * inv;
  const float A0 = fmaf(p0, c1, s1g), B0 = p0 * c1;
  const float A1 = fmaf(p1, c1, s1g), B1 = p1 * c1;
  float cA0, sA0, cB0, sB0, cA1, sA1, cB1, sB1;
  __sincosf(A0, &sA0, &cA0);
  __sincosf(B0, &sB0, &cB0);
  __sincosf(A1, &sA1, &cA1);
  __sincosf(B1, &sB1, &cB1);
  const size_t base = ((size_t)h * 2048 + row) * 128 + d;
  *(unsigned*)(Ub + base)      = (unsigned)f2bf(af0 * cA0) | ((unsigned)f2bf(af1 * cA1) << 16);
  *(unsigned*)(Ub + base + 64) = (unsigned)f2bf(af0 * sA0) | ((unsigned)f2bf(af1 * sA1) << 16);
  *(unsigned*)(Wb + base)      = (unsigned)f2bf(af0 * cB0) | ((unsigned)f2bf(af1 * cB1) << 16);
  *(unsigned*)(Wb + base + 64) = (unsigned)f2bf(af0 * sB0) | ((unsigned)f2bf(af1 * sB1) << 16);
}

// ------- single-pass MFMA flash, redundancy-free wave mapping ----------------
__global__ __launch_bounds__(512, 1) void k_flash6(const unsigned short* __restrict__ Ub,
    const unsigned short* __restrict__ Wb, const unsigned short* __restrict__ vT,
    unsigned short* __restrict__ attb) {
  __shared__ __align__(16) unsigned char s_w[2][128 * 272];  // [k][f 128 bf16 + pad]
  __shared__ __align__(16) unsigned char s_v[2][64 * 272];   // [d][k 128 bf16 + pad]
  __shared__ __align__(16) unsigned char s_p[2][64 * 272];   // [q][k 128 bf16 + pad]
  const int qt = blockIdx.x, h = blockIdx.y;
  const int q0 = qt * 64;
  const int t = threadIdx.x;
  const int wave = t >> 6, lane = t & 63;
  const int qg = wave & 3, dh = wave >> 2;
  const int m = lane & 15, quad = lane >> 4;
  const int sr = t >> 2, sp = t & 3;      // s_w staging: 128 rows x 4 parts
  const int vr = t >> 3, vp = t & 7;      // s_v staging: 64 rows x 8 parts
  short8 afr[4][4];
  #pragma unroll
  for (int g = 0; g < 4; ++g) {
    const unsigned short* urow = Ub + ((size_t)h * 2048 + q0 + g * 16 + m) * 128;
    #pragma unroll
    for (int fs = 0; fs < 4; ++fs)
      afr[g][fs] = *(const short8*)(urow + fs * 32 + quad * 8);
  }
  short8 ones;
  #pragma unroll
  for (int j = 0; j < 8; ++j) ones[j] = (short)0x3F80;   // bf16 1.0
  f32x4 oacc[2] = {{0,0,0,0},{0,0,0,0}};
  f32x4 dacc = {0, 0, 0, 0};
  const unsigned short* wgbase = Wb + (size_t)h * 2048 * 128 + (size_t)sr * 128;
  const unsigned short* vgbase = vT + ((size_t)h * 64 + vr) * 2048;
  #pragma unroll
  for (int it = 0; it < 4; ++it)
    *(short8*)(s_w[0] + sr * 272 + sp * 64 + it * 16) =
      *(const short8*)(wgbase + sp * 32 + it * 8);
  #pragma unroll
  for (int it = 0; it < 2; ++it)
    *(short8*)(s_v[0] + vr * 272 + vp * 32 + it * 16) =
      *(const short8*)(vgbase + vp * 16 + it * 8);
  __syncthreads();
  for (int kt = 0; kt < 16; ++kt) {
    const int cur = kt & 1;
    short8 wst[4], vst[2];
    const bool has = (kt < 15);
    if (has) {
      const unsigned short* wg = wgbase + (size_t)(kt + 1) * 128 * 128;
      #pragma unroll
      for (int it = 0; it < 4; ++it)
        wst[it] = *(const short8*)(wg + sp * 32 + it * 8);
      const unsigned short* vg = vgbase + (kt + 1) * 128;
      #pragma unroll
      for (int it = 0; it < 2; ++it)
        vst[it] = *(const short8*)(vg + vp * 16 + it * 8);
    }
    f32x4 sc[4] = {{0,0,0,0},{0,0,0,0},{0,0,0,0},{0,0,0,0}};
    #pragma unroll
    for (int fs = 0; fs < 4; ++fs) {
      short8 bfr = *(const short8*)(s_w[cur] + (wave * 16 + m) * 272 + fs * 64 + quad * 16);
      #pragma unroll
      for (int g = 0; g < 4; ++g)
        sc[g] = MFMA16(afr[g][fs], bfr, sc[g]);
    }
    #pragma unroll
    for (int g = 0; g < 4; ++g)
      #pragma unroll
      for (int r = 0; r < 4; ++r) {
        float p = __expf(sc[g][r] * 0.125f);
        *(unsigned short*)(s_p[cur] + (g * 16 + quad * 4 + r) * 272 +
                           (wave * 16 + m) * 2) = f2bf(p);
      }
    short8 vf[4][2];
    #pragma unroll
    for (int k2 = 0; k2 < 4; ++k2)
      #pragma unroll
      for (int dt = 0; dt < 2; ++dt)
        vf[k2][dt] = *(const short8*)(s_v[cur] + (dh * 32 + dt * 16 + m) * 272 +
                                      k2 * 64 + quad * 16);
    if (has) {
      #pragma unroll
      for (int it = 0; it < 4; ++it)
        *(short8*)(s_w[cur ^ 1] + sr * 272 + sp * 64 + it * 16) = wst[it];
      #pragma unroll
      for (int it = 0; it < 2; ++it)
        *(short8*)(s_v[cur ^ 1] + vr * 272 + vp * 32 + it * 16) = vst[it];
    }
    __syncthreads();
    #pragma unroll
    for (int k2 = 0; k2 < 4; ++k2) {
      short8 pf = *(const short8*)(s_p[cur] + (qg * 16 + m) * 272 + k2 * 64 + quad * 16);
      dacc = MFMA16(pf, ones, dacc);
      #pragma unroll
      for (int dt = 0; dt < 2; ++dt)
        oacc[dt] = MFMA16(pf, vf[k2][dt], oacc[dt]);
    }
  }
  float invd[4];
  #pragma unroll
  for (int r = 0; r < 4; ++r) invd[r] = 1.0f / dacc[r];
  #pragma unroll
  for (int dt = 0; dt < 2; ++dt)
    #pragma unroll
    for (int r = 0; r < 4; ++r)
      attb[(size_t)(q0 + qg * 16 + quad * 4 + r) * 512 + h * 64 +
           dh * 32 + dt * 16 + m] = f2bf(oacc[dt][r] * invd[r]);
}

// ------- out GEMM: out f32 = attb @ WoT^T + bo ----------------
__global__ __launch_bounds__(256) void k_gemm(const unsigned short* __restrict__ A,
    const unsigned short* __restrict__ Bt, const float* __restrict__ bias,
    float* __restrict__ C, int N) {
  __shared__ __align__(16) unsigned char sm[2 * 64 * 136];
  unsigned char* s_a = sm;
  unsigned char* s_b = sm + 64 * 136;
  const int m0 = blockIdx.x * 64, n0 = blockIdx.y * 64;
  const int t = threadIdx.x;
  const int wave = t >> 6, lane = t & 63;
  const int m = lane & 15, quad = lane >> 4;
  const int sr = t >> 2, spart = t & 3;
  f32x4 acc[4] = {{0,0,0,0},{0,0,0,0},{0,0,0,0},{0,0,0,0}};
  for (int kc = 0; kc < 512; kc += 64) {
    #pragma unroll
    for (int it = 0; it < 2; ++it) {
      *(short8*)(s_a + sr * 136 + spart * 32 + it * 16) =
        *(const short8*)(A + (size_t)(m0 + sr) * 512 + kc + spart * 16 + it * 8);
      *(short8*)(s_b + sr * 136 + spart * 32 + it * 16) =
        *(const short8*)(Bt + (size_t)(n0 + sr) * 512 + kc + spart * 16 + it * 8);
    }
    __syncthreads();
    #pragma unroll
    for (int k2 = 0; k2 < 2; ++k2) {
      short8 af = *(const short8*)(s_a + (wave * 16 + m) * 136 + k2 * 64 + quad * 16);
      #pragma unroll
      for (int nt = 0; nt < 4; ++nt) {
        short8 bf = *(const short8*)(s_b + (nt * 16 + m) * 136 + k2 * 64 + quad * 16);
        acc[nt] = MFMA16(af, bf, acc[nt]);
      }
    }
    __syncthreads();
  }
  #pragma unroll
  for (int nt = 0; nt < 4; ++nt) {
    int col = n0 + nt * 16 + m;
    float bv = bias[col];
    #pragma unroll
    for (int r = 0; r < 4; ++r) {
      int row = m0 + wave * 16 + quad * 4 + r;
      C[(size_t)row * N + col] = acc[nt][r] + bv;
    }
  }
}

extern "C" void kernel_launch(void* const* d_in, const int* in_sizes, int n_in,
                              void* d_out, int out_size, void* d_ws, size_t ws_size,
                              hipStream_t stream) {
  (void)in_sizes; (void)n_in; (void)out_size; (void)ws_size;
  const float* x   = (const float*)d_in[0];
  const float* Wq  = (const float*)d_in[1];
  const float* bq  = (const float*)d_in[2];
  const float* lnw = (const float*)d_in[3];
  const float* lnb = (const float*)d_in[4];
  const float* fr  = (const float*)d_in[5];
  const float* ps  = (const float*)d_in[6];
  const float* Wo  = (const float*)d_in[7];
  const float* bo  = (const float*)d_in[8];
  // d_in[9] = cos_table: unused (smooth-cos factorization)
  char* ws = (char*)d_ws;
  unsigned short* attb = (unsigned short*)(ws + B_ATTB);
  unsigned short* Ub   = (unsigned short*)(ws + B_UB);
  unsigned short* Wb   = (unsigned short*)(ws + B_WB);
  unsigned short* vT   = (unsigned short*)(ws + B_VT);
  unsigned short* WqTp = (unsigned short*)(ws + B_WQT);
  unsigned short* WoT  = (unsigned short*)(ws + B_WOT);
  float* qs  = (float*)(ws + B_QS);
  float* pst = (float*)(ws + B_PST);
  float* out = (float*)d_out;

  k_prep<<<448, 256, 0, stream>>>(x, Wq, Wo, vT, WqTp, WoT);
  k_qs_gemm<<<2048, 256, 0, stream>>>(x, WqTp, bq, qs, pst);
  k_ln_feat<<<2048, 256, 0, stream>>>(qs, pst, lnw, lnb, fr, ps, Ub, Wb);
  k_flash6<<<dim3(32, 8), 512, 0, stream>>>(Ub, Wb, vT, attb);
  k_gemm<<<dim3(32, 8), 256, 0, stream>>>(attb, WoT, bo, out, 512);
}